// Round 10
// baseline (133.862 us; speedup 1.0000x reference)
//
#include <hip/hip_runtime.h>
#include <hip/hip_bf16.h>

#define NB    16
#define NPT   4096
#define NSRC  1024
#define ND1   128
#define ND2   256
#define NCIN  384
#define NCMID 256
#define NCOUT 128
#define BNTOT (NB * NPT)   // 65536 points
#define BN_EPS 1e-5f

typedef float f32x4 __attribute__((ext_vector_type(4)));
typedef short bf16x8 __attribute__((ext_vector_type(8)));
typedef unsigned int uint;

union PK8 { unsigned short u[8]; uint4 q; };
union PK4 { unsigned short u[4]; uint2 q; };

static __device__ __forceinline__ unsigned short f2bf(float f) {
  __hip_bfloat16 h = __float2bfloat16(f);
  return __builtin_bit_cast(unsigned short, h);
}
static __device__ __forceinline__ float bf2f(unsigned short u) {
  return __builtin_bit_cast(float, (uint)u << 16);
}
static __device__ __forceinline__ void gl_lds16(const unsigned short* g, unsigned short* l) {
  __builtin_amdgcn_global_load_lds(
      (const __attribute__((address_space(1))) uint*)(const void*)g,
      (__attribute__((address_space(3))) uint*)(void*)l,
      16, 0, 0);
}

#if __has_builtin(__builtin_amdgcn_fmed3f)
#define MED3F(a, b, c) __builtin_amdgcn_fmed3f((a), (b), (c))
#else
#define MED3F(a, b, c) fmaxf((a), fminf((b), (c)))
#endif

// total order: (d, idx) with ties -> lower index (matches lax.top_k)
static __device__ __forceinline__ bool prec(float da, int ia, float db, int ib) {
  return (da < db) || (da == db && ia < ib);
}

// shallow branchless top-3 insert (proven rounds 5-9)
#define INSV(t0, t1, t2, j0, j1, j2, d, idx)                                   \
  {                                                                            \
    const bool c0 = (d) < t0;                                                  \
    const bool c1 = (d) < t1;                                                  \
    const bool c2 = (d) < t2;                                                  \
    const float m1 = MED3F(t0, t1, (d));                                       \
    const float m2 = fminf(t2, fmaxf(t1, (d)));                                \
    t0 = fminf(t0, (d));                                                       \
    j2 = c2 ? (c1 ? j1 : (idx)) : j2;                                          \
    j1 = c1 ? (c0 ? j0 : (idx)) : j1;                                          \
    j0 = c0 ? (idx) : j0;                                                      \
    t1 = m1; t2 = m2;                                                          \
  }

#define MERGE3(d0, j0, d1, j1, d2, j2, e0, i0, e1, i1, e2, i2)                 \
  {                                                                            \
    const bool p0 = prec(d0, j0, e0, i0);                                      \
    const float l0d = p0 ? e0 : d0; const int l0j = p0 ? i0 : j0;              \
    const float r0d = p0 ? d0 : e0; const int r0j = p0 ? j0 : i0;              \
    const bool p1 = prec(d1, j1, e1, i1);                                      \
    const float w1d = p1 ? d1 : e1; const int w1j = p1 ? j1 : i1;              \
    const bool pr1 = prec(l0d, l0j, w1d, w1j);                                 \
    const float r1d = pr1 ? l0d : w1d; const int r1j = pr1 ? l0j : w1j;        \
    const float q1d = pr1 ? w1d : l0d; const int q1j = pr1 ? w1j : l0j;        \
    const bool p2 = prec(d2, j2, e2, i2);                                      \
    const float w2d = p2 ? d2 : e2; const int w2j = p2 ? j2 : i2;              \
    const bool pr2 = prec(q1d, q1j, w2d, w2j);                                 \
    const float r2d = pr2 ? q1d : w2d; const int r2j = pr2 ? q1j : w2j;        \
    d0 = r0d; j0 = r0j; d1 = r1d; j1 = r1j; d2 = r2d; j2 = r2j;                \
  }

// ---------------- prep: W1,W2 fp32 -> bf16 ----------------
__global__ __launch_bounds__(256) void prep_w_kernel(
    const float* __restrict__ w1, const float* __restrict__ w2,
    unsigned short* __restrict__ w1b, unsigned short* __restrict__ w2b)
{
  const int i = blockIdx.x * 256 + threadIdx.x;
  const bool isW1 = i < 24576;
  const float4 v = isW1 ? ((const float4*)w1)[i] : ((const float4*)w2)[i - 24576];
  PK4 pk;
  pk.u[0] = f2bf(v.x); pk.u[1] = f2bf(v.y); pk.u[2] = f2bf(v.z); pk.u[3] = f2bf(v.w);
  if (isW1) ((uint2*)w1b)[i] = pk.q;
  else      ((uint2*)w2b)[i - 24576] = pk.q;
}

// ============ fg1 v6: reg-fragment A, 32 KB LDS, 4 blocks/CU ============
// 1024 blocks x 256 thr (4 waves), 64 pts/block. s2t aliases sB[1] (dead after
// knn); redS/redQ alias sB[0] (dead after K-loop). A fragments built in regs
// (points1 cast kt<4; 3-NN gather kt>=4 via shuffled knn results). B via
// global_load_lds double-buffer (proven r4-r9). XCD-swizzled block id.
__global__ __launch_bounds__(256, 4) void fg1_kernel(
    const float* __restrict__ xyz1, const float* __restrict__ xyz2,
    const float* __restrict__ points1, const float* __restrict__ points2,
    const unsigned short* __restrict__ W1bf, const float* __restrict__ bias1,
    unsigned short* __restrict__ h1bf, float* __restrict__ pS, float* __restrict__ pQ)
{
  __shared__ unsigned short sB[2][256][32];   // 32 KB total LDS
  float4* s2t = (float4*)&sB[1][0][0];        // 1024 slots, XOR-q layout (alias)

  const int tid = threadIdx.x;
  const int lane = tid & 63;
  const int wave = tid >> 6;

  // bijective XCD swizzle (1024 = 8 x 128): XCD x -> contiguous 128 blocks = 2 batches
  const int bid = (int)(blockIdx.x & 7) * 128 + (int)(blockIdx.x >> 3);
  const int ptBase = bid * 64;
  const int b = ptBase >> 12;

  const int fr = lane & 15;
  const int cs = lane >> 4;
  const int rdsh = ((cs ^ ((fr >> 1) & 3)) << 3);

  auto stageB = [&](int buf, int kt) {
    const int k0 = kt * 32;
#pragma unroll
    for (int c = 0; c < 4; ++c) {
      const int base = c * 256 + wave * 64;   // wave-uniform LDS chunk base
      const int s = base + lane;
      const int row = s >> 2, c16 = s & 3;
      const int ks = c16 ^ ((row >> 1) & 3);
      gl_lds16(W1bf + (size_t)row * NCIN + k0 + ks * 8, &sB[buf][0][0] + base * 8);
    }
  };

  // ---- prologue: prefetch B0 (sB[0]); stage s2t (sB[1] region, XOR-q slots) ----
  stageB(0, 0);
  {
    const float* src = xyz2 + (size_t)b * NSRC * 3 + tid * 12;
    const float4 l0 = ((const float4*)src)[0];
    const float4 l1 = ((const float4*)src)[1];
    const float4 l2 = ((const float4*)src)[2];
    const float xs[4] = {l0.x, l0.w, l1.z, l2.y};
    const float ys[4] = {l0.y, l1.x, l1.w, l2.z};
    const float zs[4] = {l0.z, l1.y, l2.x, l2.w};
#pragma unroll
    for (int u = 0; u < 4; ++u) {
      const int s = tid * 4 + u;              // global source id
      const int qq = s >> 8, ii = s & 255;
      const float c = xs[u] * xs[u] + ys[u] * ys[u] + zs[u] * zs[u];
      float4 v;
      v.x = -2.0f * xs[u]; v.y = -2.0f * ys[u]; v.z = -2.0f * zs[u]; v.w = c;
      s2t[qq * 256 + (ii ^ qq)] = v;          // XOR-q: 4 quarters -> disjoint banks
    }
  }
  __syncthreads();

  // ---- kNN phase: thread = (point tid>>2, quarter tid&3), 256 cands, 2 chains ----
  const int ptl = tid >> 2;
  const int q = tid & 3;
  const float n_ax = xyz1[(size_t)(ptBase + ptl) * 3 + 0];
  const float n_ay = xyz1[(size_t)(ptBase + ptl) * 3 + 1];
  const float n_az = xyz1[(size_t)(ptBase + ptl) * 3 + 2];
  const float n_a2 = n_ax * n_ax + n_ay * n_ay + n_az * n_az;
  const float4* n_slab = &s2t[q * 256];
  const int n_qbase = q * 256;
  const float INF = 3.4e38f;
  float n_ta0 = INF, n_ta1 = INF, n_ta2 = INF;
  float n_tb0 = INF, n_tb1 = INF, n_tb2 = INF;
  int n_ja0 = 0, n_ja1 = 0, n_ja2 = 0, n_jb0 = 0, n_jb1 = 0, n_jb2 = 0;

  for (int i = 0; i < 256; i += 2) {
    const float4 va = n_slab[i ^ q];
    float da = va.w + n_a2;
    da = fmaf(va.x, n_ax, da); da = fmaf(va.y, n_ay, da); da = fmaf(va.z, n_az, da);
    INSV(n_ta0, n_ta1, n_ta2, n_ja0, n_ja1, n_ja2, da, n_qbase + i);
    const float4 vb = n_slab[(i + 1) ^ q];
    float db = vb.w + n_a2;
    db = fmaf(vb.x, n_ax, db); db = fmaf(vb.y, n_ay, db); db = fmaf(vb.z, n_az, db);
    INSV(n_tb0, n_tb1, n_tb2, n_jb0, n_jb1, n_jb2, db, n_qbase + i + 1);
  }
  MERGE3(n_ta0, n_ja0, n_ta1, n_ja1, n_ta2, n_ja2,
         n_tb0, n_jb0, n_tb1, n_jb1, n_tb2, n_jb2);
#pragma unroll
  for (int m = 1; m <= 2; m <<= 1) {
    float e0 = __shfl_xor(n_ta0, m), e1 = __shfl_xor(n_ta1, m), e2 = __shfl_xor(n_ta2, m);
    int i0 = __shfl_xor(n_ja0, m), i1 = __shfl_xor(n_ja1, m), i2 = __shfl_xor(n_ja2, m);
    MERGE3(n_ta0, n_ja0, n_ta1, n_ja1, n_ta2, n_ja2, e0, i0, e1, i1, e2, i2);
  }
  // weights (all 4 lanes of a point hold identical triples now)
  float wq0 = 1.f / (n_ta0 + 1e-8f), wq1 = 1.f / (n_ta1 + 1e-8f), wq2 = 1.f / (n_ta2 + 1e-8f);
  const float winv = 1.f / (wq0 + wq1 + wq2);
  wq0 *= winv; wq1 *= winv; wq2 *= winv;

  // redistribute: lane (fr,cs) owns A-row 16*wave+fr; knn result lives in lane 4*fr
  const int srcl = 4 * fr;
  const int j0r = __shfl(n_ja0, srcl);
  const int j1r = __shfl(n_ja1, srcl);
  const int j2r = __shfl(n_ja2, srcl);
  const float gw0 = __shfl(wq0, srcl);
  const float gw1 = __shfl(wq1, srcl);
  const float gw2 = __shfl(wq2, srcl);
  const float* p2base = points2 + (size_t)b * NSRC * ND2;
  const float* g0p = p2base + (size_t)j0r * ND2;
  const float* g1p = p2base + (size_t)j1r * ND2;
  const float* g2p = p2base + (size_t)j2r * ND2;

  __syncthreads();   // all knn reads of s2t done -> sB[1] reusable

  // ---- K-loop: A fragment in regs, B from LDS, 16 MFMA/kt ----
  f32x4 acc[16];
#pragma unroll
  for (int j = 0; j < 16; ++j)
#pragma unroll
    for (int p = 0; p < 4; ++p) acc[j][p] = 0.0f;

  const int arow = ptBase + wave * 16 + fr;   // this lane's A row (global point)
  int buf = 0;
  for (int kt = 0; kt < 12; ++kt) {
    if (kt < 11) stageB(buf ^ 1, kt + 1);
    const int k = kt * 32 + cs * 8;
    PK8 af;
    if (kt < 4) {                             // points1 cast (32 B contiguous)
      const float* src = points1 + (size_t)arow * ND1 + k;
      const float4 va = ((const float4*)src)[0];
      const float4 vb = ((const float4*)src)[1];
      af.u[0] = f2bf(va.x); af.u[1] = f2bf(va.y); af.u[2] = f2bf(va.z); af.u[3] = f2bf(va.w);
      af.u[4] = f2bf(vb.x); af.u[5] = f2bf(vb.y); af.u[6] = f2bf(vb.z); af.u[7] = f2bf(vb.w);
    } else {                                  // 3-NN gather + combine
      const int ko = k - ND1;
      const float4* r0 = (const float4*)(g0p + ko);
      const float4* r1 = (const float4*)(g1p + ko);
      const float4* r2 = (const float4*)(g2p + ko);
#pragma unroll
      for (int h = 0; h < 2; ++h) {
        const float4 va = r0[h], vb = r1[h], vc = r2[h];
        af.u[h * 4 + 0] = f2bf(gw0 * va.x + gw1 * vb.x + gw2 * vc.x);
        af.u[h * 4 + 1] = f2bf(gw0 * va.y + gw1 * vb.y + gw2 * vc.y);
        af.u[h * 4 + 2] = f2bf(gw0 * va.z + gw1 * vb.z + gw2 * vc.z);
        af.u[h * 4 + 3] = f2bf(gw0 * va.w + gw1 * vb.w + gw2 * vc.w);
      }
    }
    const bf16x8 a = __builtin_bit_cast(bf16x8, af.q);
#pragma unroll
    for (int j = 0; j < 16; ++j) {
      const bf16x8 bv = *(const bf16x8*)&sB[buf][j * 16 + fr][rdsh];
      acc[j] = __builtin_amdgcn_mfma_f32_16x16x32_bf16(a, bv, acc[j], 0, 0, 0);
    }
    __syncthreads();
    buf ^= 1;
  }

  // ---- epilogue: h1bf store + BN1 partials (redS/redQ alias sB[0]) ----
  float* redS = (float*)&sB[0][0][0];         // 4 KB
  float* redQ = redS + 1024;                  // 4 KB
  const int r0 = cs * 4;
#pragma unroll
  for (int j = 0; j < 16; ++j) {
    const int ch = j * 16 + fr;
    const float bb = bias1[ch];
    float s = 0.f, s2 = 0.f;
#pragma unroll
    for (int p = 0; p < 4; ++p) {
      const int pt = ptBase + wave * 16 + r0 + p;
      const float v = acc[j][p] + bb;
      h1bf[(size_t)pt * NCMID + ch] = f2bf(v);
      s += v; s2 += v * v;
    }
    s += __shfl_xor(s, 16);  s2 += __shfl_xor(s2, 16);
    s += __shfl_xor(s, 32);  s2 += __shfl_xor(s2, 32);
    if (cs == 0) { redS[wave * 256 + ch] = s; redQ[wave * 256 + ch] = s2; }
  }
  __syncthreads();
  {
    const int ch = tid;
    const float s  = redS[ch] + redS[256 + ch] + redS[512 + ch] + redS[768 + ch];
    const float s2 = redQ[ch] + redQ[256 + ch] + redQ[512 + ch] + redQ[768 + ch];
    pS[(size_t)bid * NCMID + ch] = s;
    pQ[(size_t)bid * NCMID + ch] = s2;
  }
}

// ---------------- reduce per-block BN1 partials (1024 rows -> 32 atomics) ----------------
__global__ __launch_bounds__(256) void colred_kernel(
    const float* __restrict__ pS, const float* __restrict__ pQ,
    float* __restrict__ sum1, float* __restrict__ sq1)
{
  const int ch = threadIdx.x;
  const int r0 = blockIdx.x * 32;
  float s = 0.f, s2 = 0.f;
  for (int i = 0; i < 32; ++i) {
    s  += pS[(size_t)(r0 + i) * NCMID + ch];
    s2 += pQ[(size_t)(r0 + i) * NCMID + ch];
  }
  atomicAdd(&sum1[ch], s);
  atomicAdd(&sq1[ch], s2);
}

// ---------------- fold BN into per-channel affine: y = a*x + d ----------------
template <int C>
__global__ void stats_kernel(const float* __restrict__ sum, const float* __restrict__ sumsq,
                             const float* __restrict__ g, const float* __restrict__ be,
                             float* __restrict__ a, float* __restrict__ d)
{
  const int c = threadIdx.x;
  const float mean = sum[c] * (1.0f / BNTOT);
  const float var = sumsq[c] * (1.0f / BNTOT) - mean * mean;
  const float inv = rsqrtf(var + BN_EPS);
  const float ac = g[c] * inv;
  a[c] = ac;
  d[c] = be[c] - mean * ac;
}

// ---------------- GEMM2 (+fused BN2 column sums, bf16 out) — proven r5-r9 ----------------
__global__ __launch_bounds__(256, 2) void gemm2_kernel(
    const unsigned short* __restrict__ h1bf, const unsigned short* __restrict__ W2bf,
    const float* __restrict__ bias2, const float* __restrict__ aff_a,
    const float* __restrict__ aff_d, unsigned short* __restrict__ h2bf,
    float* __restrict__ sum2, float* __restrict__ sq2)
{
  __shared__ unsigned short sA[2][128][32];
  __shared__ unsigned short sB[2][128][32];
  __shared__ float sa[NCMID], sd[NCMID];
  const int tid = threadIdx.x;
  const int lane = tid & 63;
  const int wave = tid >> 6;
  const int ptBase = blockIdx.x * 128;
  sa[tid] = aff_a[tid];
  sd[tid] = aff_d[tid];

  f32x4 acc[2][8];
#pragma unroll
  for (int m = 0; m < 2; ++m)
#pragma unroll
    for (int j = 0; j < 8; ++j)
#pragma unroll
      for (int q = 0; q < 4; ++q) acc[m][j][q] = 0.0f;

  const int fr = lane & 15;
  const int cs = lane >> 4;
  const int rdsh = ((cs ^ ((fr >> 1) & 3)) << 3);

  auto stageB = [&](int buf, int kt) {
    const int k0 = kt * 32;
#pragma unroll
    for (int c = 0; c < 2; ++c) {
      const int s = c * 256 + wave * 64 + lane;
      const int row = s >> 2, c16 = s & 3;
      const int ks = c16 ^ ((row >> 1) & 3);
      gl_lds16(W2bf + (size_t)row * NCMID + k0 + ks * 8,
               &sB[buf][0][0] + (c * 256 + wave * 64) * 8);
    }
  };
  auto stageA = [&](int buf, int kt) {
    const int k0 = kt * 32;
#pragma unroll
    for (int c = 0; c < 2; ++c) {
      const int s = c * 256 + tid;
      const int row = s >> 2, c16 = s & 3;
      const int ks = c16 ^ ((row >> 1) & 3);
      const int k = k0 + ks * 8;
      PK8 v;
      v.q = *(const uint4*)(h1bf + (size_t)(ptBase + row) * NCMID + k);
      PK8 pk;
#pragma unroll
      for (int j = 0; j < 8; ++j)
        pk.u[j] = f2bf(fmaxf(0.f, sa[k + j] * bf2f(v.u[j]) + sd[k + j]));
      *(uint4*)(&sA[buf][0][0] + s * 8) = pk.q;
    }
  };

  stageB(0, 0);
  __syncthreads();
  stageA(0, 0);
  __syncthreads();
  int cur = 0;
  for (int kt = 0; kt < 8; ++kt) {
    if (kt < 7) { stageB(cur ^ 1, kt + 1); stageA(cur ^ 1, kt + 1); }
    const bf16x8 a0 = *(const bf16x8*)&sA[cur][wave * 32 + fr][rdsh];
    const bf16x8 a1 = *(const bf16x8*)&sA[cur][wave * 32 + 16 + fr][rdsh];
#pragma unroll
    for (int j = 0; j < 8; ++j) {
      const bf16x8 b = *(const bf16x8*)&sB[cur][j * 16 + fr][rdsh];
      acc[0][j] = __builtin_amdgcn_mfma_f32_16x16x32_bf16(a0, b, acc[0][j], 0, 0, 0);
      acc[1][j] = __builtin_amdgcn_mfma_f32_16x16x32_bf16(a1, b, acc[1][j], 0, 0, 0);
    }
    __syncthreads();
    cur ^= 1;
  }

  float* redS = (float*)&sA[0][0][0];
  float* redQ = redS + 512;
  const int col = fr;
  const int r0 = cs * 4;
#pragma unroll
  for (int j = 0; j < 8; ++j) {
    const int ch = j * 16 + col;
    const float bb = bias2[ch];
    float s = 0.f, s2 = 0.f;
#pragma unroll
    for (int m = 0; m < 2; ++m)
#pragma unroll
      for (int q = 0; q < 4; ++q) {
        const int pt = ptBase + wave * 32 + m * 16 + r0 + q;
        const float v = acc[m][j][q] + bb;
        h2bf[(size_t)pt * NCOUT + ch] = f2bf(v);
        s += v; s2 += v * v;
      }
    s += __shfl_xor(s, 16);  s2 += __shfl_xor(s2, 16);
    s += __shfl_xor(s, 32);  s2 += __shfl_xor(s2, 32);
    if (cs == 0) { redS[wave * 128 + fr * 8 + j] = s; redQ[wave * 128 + fr * 8 + j] = s2; }
  }
  __syncthreads();
  if (tid < NCOUT) {
    const int ch = tid;
    const int f = ch & 15, j = ch >> 4;
    float s = 0.f, s2 = 0.f;
#pragma unroll
    for (int w = 0; w < 4; ++w) {
      s  += redS[w * 128 + f * 8 + j];
      s2 += redQ[w * 128 + f * 8 + j];
    }
    atomicAdd(&sum2[ch], s);
    atomicAdd(&sq2[ch], s2);
  }
}

// ---------------- final: BN2-affine + ReLU, bf16 h2 -> fp32 out ----------------
__global__ __launch_bounds__(256) void final_kernel(
    const unsigned short* __restrict__ h2bf, float* __restrict__ out,
    const float* __restrict__ a2, const float* __restrict__ d2)
{
  __shared__ float sa[NCOUT], sd[NCOUT];
  if (threadIdx.x < NCOUT) { sa[threadIdx.x] = a2[threadIdx.x]; sd[threadIdx.x] = d2[threadIdx.x]; }
  __syncthreads();
  const int total8 = BNTOT * NCOUT / 8;
  for (int i = blockIdx.x * blockDim.x + threadIdx.x; i < total8;
       i += gridDim.x * blockDim.x) {
    PK8 v; v.q = ((const uint4*)h2bf)[i];
    const int c = (i & 15) * 8;
    float4 o0, o1;
    o0.x = fmaxf(0.f, sa[c + 0] * bf2f(v.u[0]) + sd[c + 0]);
    o0.y = fmaxf(0.f, sa[c + 1] * bf2f(v.u[1]) + sd[c + 1]);
    o0.z = fmaxf(0.f, sa[c + 2] * bf2f(v.u[2]) + sd[c + 2]);
    o0.w = fmaxf(0.f, sa[c + 3] * bf2f(v.u[3]) + sd[c + 3]);
    o1.x = fmaxf(0.f, sa[c + 4] * bf2f(v.u[4]) + sd[c + 4]);
    o1.y = fmaxf(0.f, sa[c + 5] * bf2f(v.u[5]) + sd[c + 5]);
    o1.z = fmaxf(0.f, sa[c + 6] * bf2f(v.u[6]) + sd[c + 6]);
    o1.w = fmaxf(0.f, sa[c + 7] * bf2f(v.u[7]) + sd[c + 7]);
    ((float4*)out)[i * 2]     = o0;
    ((float4*)out)[i * 2 + 1] = o1;
  }
}

extern "C" void kernel_launch(void* const* d_in, const int* in_sizes, int n_in,
                              void* d_out, int out_size, void* d_ws, size_t ws_size,
                              hipStream_t stream) {
  const float* xyz1    = (const float*)d_in[0];
  const float* xyz2    = (const float*)d_in[1];
  const float* points1 = (const float*)d_in[2];
  const float* points2 = (const float*)d_in[3];
  const float* W1      = (const float*)d_in[4];
  const float* b1      = (const float*)d_in[5];
  const float* g1      = (const float*)d_in[6];
  const float* be1     = (const float*)d_in[7];
  const float* W2      = (const float*)d_in[8];
  const float* b2      = (const float*)d_in[9];
  const float* g2      = (const float*)d_in[10];
  const float* be2     = (const float*)d_in[11];
  float* out = (float*)d_out;

  char* ws = (char*)d_ws;
  const size_t h1_bytes  = (size_t)BNTOT * NCMID * 2;    // 32 MB
  const size_t h2_bytes  = (size_t)BNTOT * NCOUT * 2;    // 16 MB
  const size_t w1b_bytes = (size_t)NCMID * NCIN * 2;     // 192 KB
  const size_t w2b_bytes = (size_t)NCOUT * NCMID * 2;    // 64 KB
  const size_t ps_bytes  = (size_t)1024 * NCMID * 4;     // 1 MB
  unsigned short* h1bf = (unsigned short*)ws;
  unsigned short* h2bf = (unsigned short*)(ws + h1_bytes);
  unsigned short* W1bf = (unsigned short*)(ws + h1_bytes + h2_bytes);
  unsigned short* W2bf = (unsigned short*)(ws + h1_bytes + h2_bytes + w1b_bytes);
  float* pS = (float*)(ws + h1_bytes + h2_bytes + w1b_bytes + w2b_bytes);
  float* pQ = (float*)(ws + h1_bytes + h2_bytes + w1b_bytes + w2b_bytes + ps_bytes);
  float* stats = (float*)(ws + h1_bytes + h2_bytes + w1b_bytes + w2b_bytes + 2 * ps_bytes);
  float* sum1 = stats;
  float* sq1  = stats + 256;
  float* sum2 = stats + 512;
  float* sq2  = stats + 640;
  float* a1   = stats + 768;
  float* dd1  = stats + 1024;
  float* a2v  = stats + 1280;
  float* dd2v = stats + 1408;

  hipMemsetAsync(stats, 0, 768 * sizeof(float), stream);

  prep_w_kernel<<<128, 256, 0, stream>>>(W1, W2, W1bf, W2bf);
  fg1_kernel<<<1024, 256, 0, stream>>>(xyz1, xyz2, points1, points2,
                                       W1bf, b1, h1bf, pS, pQ);
  colred_kernel<<<32, 256, 0, stream>>>(pS, pQ, sum1, sq1);
  stats_kernel<NCMID><<<1, NCMID, 0, stream>>>(sum1, sq1, g1, be1, a1, dd1);
  gemm2_kernel<<<BNTOT / 128, 256, 0, stream>>>(h1bf, W2bf, b2, a1, dd1, h2bf, sum2, sq2);
  stats_kernel<NCOUT><<<1, NCOUT, 0, stream>>>(sum2, sq2, g2, be2, a2v, dd2v);
  final_kernel<<<2048, 256, 0, stream>>>(h2bf, out, a2v, dd2v);
}